// Round 8
// baseline (705.843 us; speedup 1.0000x reference)
//
#include <hip/hip_runtime.h>
#include <math.h>

#define N_TOK 8192
#define C_DIM 1024
#define D_DIM 3072
#define E_NUM 8
#define SEG 256
#define MAXB 72    // sum ceil(cnt_e/256) <= 64 + 8; 72*24 and 72*8 divisible by 8

typedef unsigned short u16;
typedef unsigned int u32;
typedef __attribute__((ext_vector_type(8))) short bf16x8;
typedef __attribute__((ext_vector_type(4))) float f32x4;

__device__ __forceinline__ u16 f2bf(float f) {
  u32 u = __builtin_bit_cast(unsigned int, f);
  u = (u + 0x7FFFu + ((u >> 16) & 1u)) >> 16;
  return (u16)u;
}

__device__ __forceinline__ void gl_lds16(const void* g, void* l) {
  __builtin_amdgcn_global_load_lds(
      (const __attribute__((address_space(1))) unsigned int*)g,
      (__attribute__((address_space(3))) unsigned int*)l, 16, 0, 0);
}

// fused counted-vmcnt wait + barrier (asm so the compiler can't drain vmcnt to 0)
template<int N> __device__ __forceinline__ void wait_bar() {
  if constexpr (N == 0) asm volatile("s_waitcnt vmcnt(0)\n\ts_barrier" ::: "memory");
  else if constexpr (N == 3) asm volatile("s_waitcnt vmcnt(3)\n\ts_barrier" ::: "memory");
  else if constexpr (N == 4) asm volatile("s_waitcnt vmcnt(4)\n\ts_barrier" ::: "memory");
}
__device__ __forceinline__ void bar_only() {
  asm volatile("s_barrier" ::: "memory");
}

// ---------------- init: zero output (incl aux loss) + counters ----------------
__global__ void zero_init_kernel(float* __restrict__ out, int n, int* __restrict__ cnt) {
  int i = blockIdx.x * 256 + threadIdx.x;
  if (i < n) out[i] = 0.0f;
  if (i < E_NUM) cnt[i] = 0;
}

// -------- transpose+convert: in [E][R][CC] f32 -> out [E][CC][R] bf16 --------
template<int R, int CC>
__global__ __launch_bounds__(256) void transpose_conv_kernel(
    const float* __restrict__ in, u16* __restrict__ outp) {
  __shared__ float t[64][65];
  const int e = blockIdx.z;
  const int r0 = blockIdx.y * 64;
  const int c0 = blockIdx.x * 64;
  const int tid = threadIdx.x;
  const int lr = tid >> 4;
  const int lc = (tid & 15) * 4;
#pragma unroll
  for (int i = 0; i < 4; i++) {
    float4 v = *(const float4*)(in + ((size_t)e * R + r0 + lr + i * 16) * CC + c0 + lc);
    t[lr + i * 16][lc] = v.x; t[lr + i * 16][lc + 1] = v.y;
    t[lr + i * 16][lc + 2] = v.z; t[lr + i * 16][lc + 3] = v.w;
  }
  __syncthreads();
  const int orow = tid >> 3;
  const int oc = (tid & 7) * 8;
#pragma unroll
  for (int i = 0; i < 2; i++) {
    const int d = orow + i * 32;
    union { u16 s[8]; uint4 v; } o;
#pragma unroll
    for (int j = 0; j < 8; j++) o.s[j] = f2bf(t[oc + j][d]);
    *(uint4*)(outp + ((size_t)e * CC + c0 + d) * R + r0 + oc) = o.v;
  }
}

// ---------------- router: logits (fp64), top-2, scatter ----------------
__global__ void router_kernel(const float* __restrict__ x, const float* __restrict__ rw,
                              int* __restrict__ cnt, int* __restrict__ list,
                              float* __restrict__ wl) {
  const int lane = threadIdx.x & 63;
  const int n = blockIdx.x * 4 + (threadIdx.x >> 6);
  const float* xr = x + (size_t)n * C_DIM;
  double acc[E_NUM];
#pragma unroll
  for (int e = 0; e < E_NUM; e++) acc[e] = 0.0;
  for (int c = lane; c < C_DIM; c += 64) {
    float xv = xr[c];
#pragma unroll
    for (int e = 0; e < E_NUM; e++) acc[e] += (double)xv * (double)rw[e * C_DIM + c];
  }
#pragma unroll
  for (int e = 0; e < E_NUM; e++) {
    double v = acc[e];
#pragma unroll
    for (int off = 32; off > 0; off >>= 1) v += __shfl_down(v, off, 64);
    acc[e] = v;
  }
  if (lane == 0) {
    int i0 = 0;
#pragma unroll
    for (int e = 1; e < E_NUM; e++) if (acc[e] > acc[i0]) i0 = e;
    int i1 = (i0 == 0) ? 1 : 0;
#pragma unroll
    for (int e = 0; e < E_NUM; e++) if (e != i0 && acc[e] > acc[i1]) i1 = e;
    double d = acc[i0] - acc[i1];          // >= 0
    double w0 = 1.0 / (1.0 + exp(-d));     // p0/(p0+p1)
    double w1 = 1.0 - w0;
    int p0 = atomicAdd(&cnt[i0], 1);
    list[i0 * N_TOK + p0] = n; wl[i0 * N_TOK + p0] = (float)w0;
    int p1 = atomicAdd(&cnt[i1], 1);
    list[i1 * N_TOK + p1] = n; wl[i1 * N_TOK + p1] = (float)w1;
  }
}

// ---------------- prefix sum + block table (SEG-row segments) ----------------
__global__ void prefix_kernel(const int* __restrict__ cnt, int* __restrict__ rowbase,
                              int* __restrict__ btab) {
  if (threadIdx.x == 0) {
    int s = 0, nb = 0;
    for (int e = 0; e < E_NUM; e++) {
      rowbase[e] = s;
      for (int m0 = 0; m0 < cnt[e]; m0 += SEG) { btab[2 * nb] = e; btab[2 * nb + 1] = m0; nb++; }
      s += cnt[e];
    }
    for (; nb < MAXB; nb++) { btab[2 * nb] = -1; btab[2 * nb + 1] = 0; }
  }
}

// ---------------- gather + convert: Xg[rb+p] = bf16(x[list[e][p]]) ----------------
__global__ void gather_x_kernel(const float* __restrict__ x, const int* __restrict__ cnt,
                                const int* __restrict__ rowbase, const int* __restrict__ list,
                                u16* __restrict__ Xg) {
  const int e = blockIdx.y;
  const int p = blockIdx.x * 4 + (threadIdx.x >> 6);
  if (p >= cnt[e]) return;
  const int lane = threadIdx.x & 63;
  const int tok = list[e * N_TOK + p];
  const float* src = x + (size_t)tok * C_DIM;
  u16* dst = Xg + (size_t)(rowbase[e] + p) * C_DIM;
#pragma unroll
  for (int i = 0; i < 4; i++) {
    float4 v = *(const float4*)(src + lane * 4 + i * 256);
    ushort4 o;
    o.x = f2bf(v.x); o.y = f2bf(v.y); o.z = f2bf(v.z); o.w = f2bf(v.w);
    *(ushort4*)(dst + lane * 4 + i * 256) = o;
  }
}

// ------- 256x128 tile, 512 threads (8 waves 2x4), 48KB LDS dbuf, 2 blocks/CU -------
// AI = 85.3 flop/byte staged (vs 64 for 128^2): staged-BW-bound throughput +33%.
// Source-XOR swizzle (involution within each row's 64B) + swizzled ds_read: no bank conflicts.
// EPI=1: h = gelu(Xg @ W1t^T + b1)     A=Xg dense rows, Wt=[E][D][C]
// EPI=2: out += w*(h @ W2t^T + b2)     A=h dense rows,  Wt=[E][C][D]
template<int NN0, int K, int EPI>
__global__ __launch_bounds__(512, 4) void gemm_big_kernel(
    const u16* __restrict__ A, const u16* __restrict__ Wt, const float* __restrict__ bias_,
    const int* __restrict__ btab, const int* __restrict__ cnt, const int* __restrict__ rowbase,
    const int* __restrict__ list, const float* __restrict__ wl,
    u16* __restrict__ hout, float* __restrict__ out) {
  constexpr int NTOT = NN0 * 128;
  constexpr int NT = K / 32;       // K-steps
  constexpr int TOT = MAXB * NN0;  // grid (TOT % 8 == 0)

  __shared__ __align__(16) u16 ldsA[2 * 256 * 32];  // 32 KB
  __shared__ __align__(16) u16 ldsB[2 * 128 * 32];  // 16 KB

  // bijective XCD chunking; n0-minor: co-resident blocks share A-panels
  const int L = (blockIdx.x & 7) * (TOT / 8) + (blockIdx.x >> 3);
  const int bx = L / NN0;
  const int n0 = (L % NN0) * 128;

  const int e = btab[bx * 2];
  if (e < 0) return;
  const int m0 = btab[bx * 2 + 1];
  const int count = cnt[e];
  const int rb = rowbase[e];

  const int tid = threadIdx.x;
  const int lane = tid & 63;
  const int wid = tid >> 6;
  const int wm = (wid >> 2) * 128;   // 2 M-waves
  const int wn = (wid & 3) * 32;     // 4 N-waves
  const int l15 = lane & 15, l4 = lane >> 4;

  // staging: chunk c = tid + r*512; row = c>>2; source pos XOR'd by (row>>1)&3
  // (involution within the row's 64B -> 64B-granule coalescing preserved)
  const int cs8 = ((tid & 3) ^ ((tid >> 3) & 3)) * 8;
  const int ar0 = tid >> 2;
  const u16* aptr0 = A + (size_t)(rb + min(m0 + ar0, count - 1)) * K + cs8;
  const u16* aptr1 = A + (size_t)(rb + min(m0 + ar0 + 128, count - 1)) * K + cs8;
  const u16* bptr0 = Wt + ((size_t)e * NTOT + n0 + ar0) * K + cs8;

  // swizzled fragment read offsets: key = (l15>>1)&3 (invariant under +16-row steps)
  const int key = (l15 >> 1) & 3;
  const int paoff = (wm + l15) * 32 + ((l4 ^ key) * 8);
  const int pboff = (wn + l15) * 32 + ((l4 ^ key) * 8);

  f32x4 acc[8][2];
#pragma unroll
  for (int i = 0; i < 8; i++)
#pragma unroll
    for (int j = 0; j < 2; j++) acc[i][j] = {0.f, 0.f, 0.f, 0.f};

  auto STAGE = [&](int t, int b) {
    u16* da = ldsA + b * 8192 + tid * 8;
    u16* db = ldsB + b * 4096 + tid * 8;
    const int ko = t * 32;
    gl_lds16(aptr0 + ko, da);
    gl_lds16(aptr1 + ko, da + 4096);
    gl_lds16(bptr0 + ko, db);
  };

  auto PHASE = [&](int b) {
    const u16* pa = ldsA + b * 8192 + paoff;
    const u16* pb = ldsB + b * 4096 + pboff;
    bf16x8 bv0 = *(const bf16x8*)(pb);
    bf16x8 bv1 = *(const bf16x8*)(pb + 512);
#pragma unroll
    for (int i = 0; i < 8; i++) {
      bf16x8 av = *(const bf16x8*)(pa + i * 512);
      acc[i][0] = __builtin_amdgcn_mfma_f32_16x16x32_bf16(av, bv0, acc[i][0], 0, 0, 0);
      acc[i][1] = __builtin_amdgcn_mfma_f32_16x16x32_bf16(av, bv1, acc[i][1], 0, 0, 0);
    }
  };

  // double-buffer, counted vmcnt: prefetch of t+1 stays in flight across the barrier
  STAGE(0, 0);
#pragma unroll 2
  for (int t = 0; t < NT - 1; ++t) {
    STAGE(t + 1, (t + 1) & 1);
    wait_bar<3>();            // t's 3 loads landed; t+1's may fly
    PHASE(t & 1);
    bar_only();               // all waves done reading buf t&1 before overwrite
  }
  wait_bar<0>();
  PHASE((NT - 1) & 1);

  // ---------------- epilogue ----------------
  if constexpr (EPI == 1) {
#pragma unroll
    for (int i = 0; i < 8; i++) {
      const int rloc = wm + i * 16 + l4 * 4;
#pragma unroll
      for (int j = 0; j < 2; j++) {
        const int col = n0 + wn + j * 16 + l15;
        const float bias = bias_[e * NTOT + col];
#pragma unroll
        for (int rr = 0; rr < 4; rr++) {
          const int m = m0 + rloc + rr;
          if (m < count) {
            float v = acc[i][j][rr] + bias;
            float g = 0.5f * v * (1.0f + erff(v * 0.70710678118654752f));
            hout[(size_t)(rb + m) * D_DIM + col] = f2bf(g);
          }
        }
      }
    }
  } else {
    const int* lst = list + e * N_TOK;
    const float* wlst = wl + e * N_TOK;
#pragma unroll
    for (int i = 0; i < 8; i++) {
      const int rloc = wm + i * 16 + l4 * 4;
#pragma unroll
      for (int j = 0; j < 2; j++) {
        const int col = n0 + wn + j * 16 + l15;
        const float bias = bias_[e * NTOT + col];
#pragma unroll
        for (int rr = 0; rr < 4; rr++) {
          const int m = m0 + rloc + rr;
          if (m < count) {
            const int tk = lst[m];
            atomicAdd(out + (size_t)tk * C_DIM + col, wlst[m] * (acc[i][j][rr] + bias));
          }
        }
      }
    }
  }
}

extern "C" void kernel_launch(void* const* d_in, const int* in_sizes, int n_in,
                              void* d_out, int out_size, void* d_ws, size_t ws_size,
                              hipStream_t stream) {
  const float* x  = (const float*)d_in[0];
  const float* rw = (const float*)d_in[1];
  const float* W1 = (const float*)d_in[2];
  const float* b1 = (const float*)d_in[3];
  const float* W2 = (const float*)d_in[4];
  const float* b2 = (const float*)d_in[5];
  float* out = (float*)d_out;

  char* ws = (char*)d_ws;
  u16* W1t    = (u16*)(ws);                      // 50,331,648 B
  u16* Xg     = (u16*)(ws + 50331648);           // 33,554,432 B (overlaid by W2t after gemm1)
  u16* W2t    = (u16*)(ws + 50331648);           // 50,331,648 B (written AFTER gemm1)
  int* cnt    = (int*)(ws + 100663296);          // 256 B
  int* rowbase= (int*)(ws + 100663552);          // 256 B
  int* list   = (int*)(ws + 100663808);          // 262,144 B
  float* wl   = (float*)(ws + 100925952);        // 262,144 B
  int* btab   = (int*)(ws + 101188096);          // 2,048 B
  u16* h      = (u16*)(ws + 101190656);          // 100,663,296 B -> end 201,853,952

  zero_init_kernel<<<(out_size + 255) / 256, 256, 0, stream>>>(out, out_size, cnt);
  router_kernel<<<N_TOK / 4, 256, 0, stream>>>(x, rw, cnt, list, wl);
  prefix_kernel<<<1, 64, 0, stream>>>(cnt, rowbase, btab);
  gather_x_kernel<<<dim3(N_TOK / 4, E_NUM), 256, 0, stream>>>(x, cnt, rowbase, list, Xg);
  // W1 [E][C][D] f32 -> W1t [E][D][C] bf16
  transpose_conv_kernel<C_DIM, D_DIM><<<dim3(D_DIM / 64, C_DIM / 64, E_NUM), 256, 0, stream>>>(W1, W1t);
  gemm_big_kernel<24, C_DIM, 1><<<MAXB * 24, 512, 0, stream>>>(
      Xg, W1t, b1, btab, cnt, rowbase, list, wl, h, out);
  // W2 [E][D][C] f32 -> W2t [E][C][D] bf16
  transpose_conv_kernel<D_DIM, C_DIM><<<dim3(C_DIM / 64, D_DIM / 64, E_NUM), 256, 0, stream>>>(W2, W2t);
  gemm_big_kernel<8, D_DIM, 2><<<MAXB * 8, 512, 0, stream>>>(
      h, W2t, b2, btab, cnt, rowbase, list, wl, h, out);
}

// Round 9
// 698.353 us; speedup vs baseline: 1.0107x; 1.0107x over previous
//
#include <hip/hip_runtime.h>
#include <math.h>

#define N_TOK 8192
#define C_DIM 1024
#define D_DIM 3072
#define E_NUM 8
#define MAXB 136    // SEG=128 table (gemm2)
#define MAXB2 72    // SEG=256 table (gemm1)

typedef unsigned short u16;
typedef unsigned int u32;
typedef __attribute__((ext_vector_type(8))) short bf16x8;
typedef __attribute__((ext_vector_type(4))) float f32x4;

__device__ __forceinline__ u16 f2bf(float f) {
  u32 u = __builtin_bit_cast(unsigned int, f);
  u = (u + 0x7FFFu + ((u >> 16) & 1u)) >> 16;
  return (u16)u;
}

__device__ __forceinline__ void gl_lds16(const void* g, void* l) {
  __builtin_amdgcn_global_load_lds(
      (const __attribute__((address_space(1))) unsigned int*)g,
      (__attribute__((address_space(3))) unsigned int*)l, 16, 0, 0);
}

// fused counted-vmcnt wait + barrier (asm so the compiler can't drain vmcnt to 0)
template<int N> __device__ __forceinline__ void wait_bar() {
  if constexpr (N == 0) asm volatile("s_waitcnt vmcnt(0)\n\ts_barrier" ::: "memory");
  else if constexpr (N == 2) asm volatile("s_waitcnt vmcnt(2)\n\ts_barrier" ::: "memory");
  else if constexpr (N == 4) asm volatile("s_waitcnt vmcnt(4)\n\ts_barrier" ::: "memory");
  else if constexpr (N == 6) asm volatile("s_waitcnt vmcnt(6)\n\ts_barrier" ::: "memory");
}
__device__ __forceinline__ void bar_only() {
  asm volatile("s_barrier" ::: "memory");
}

// ---------------- init: zero output (incl aux loss) + counters ----------------
__global__ void zero_init_kernel(float* __restrict__ out, int n, int* __restrict__ cnt) {
  int i = blockIdx.x * 256 + threadIdx.x;
  if (i < n) out[i] = 0.0f;
  if (i < E_NUM) cnt[i] = 0;
}

// -------- transpose+convert: in [E][R][CC] f32 -> out [E][CC][R] bf16 --------
template<int R, int CC>
__global__ __launch_bounds__(256) void transpose_conv_kernel(
    const float* __restrict__ in, u16* __restrict__ outp) {
  __shared__ float t[64][65];
  const int e = blockIdx.z;
  const int r0 = blockIdx.y * 64;
  const int c0 = blockIdx.x * 64;
  const int tid = threadIdx.x;
  const int lr = tid >> 4;
  const int lc = (tid & 15) * 4;
#pragma unroll
  for (int i = 0; i < 4; i++) {
    float4 v = *(const float4*)(in + ((size_t)e * R + r0 + lr + i * 16) * CC + c0 + lc);
    t[lr + i * 16][lc] = v.x; t[lr + i * 16][lc + 1] = v.y;
    t[lr + i * 16][lc + 2] = v.z; t[lr + i * 16][lc + 3] = v.w;
  }
  __syncthreads();
  const int orow = tid >> 3;
  const int oc = (tid & 7) * 8;
#pragma unroll
  for (int i = 0; i < 2; i++) {
    const int d = orow + i * 32;
    union { u16 s[8]; uint4 v; } o;
#pragma unroll
    for (int j = 0; j < 8; j++) o.s[j] = f2bf(t[oc + j][d]);
    *(uint4*)(outp + ((size_t)e * CC + c0 + d) * R + r0 + oc) = o.v;
  }
}

// ---------------- router: logits (fp64), top-2, scatter ----------------
__global__ void router_kernel(const float* __restrict__ x, const float* __restrict__ rw,
                              int* __restrict__ cnt, int* __restrict__ list,
                              float* __restrict__ wl) {
  const int lane = threadIdx.x & 63;
  const int n = blockIdx.x * 4 + (threadIdx.x >> 6);
  const float* xr = x + (size_t)n * C_DIM;
  double acc[E_NUM];
#pragma unroll
  for (int e = 0; e < E_NUM; e++) acc[e] = 0.0;
  for (int c = lane; c < C_DIM; c += 64) {
    float xv = xr[c];
#pragma unroll
    for (int e = 0; e < E_NUM; e++) acc[e] += (double)xv * (double)rw[e * C_DIM + c];
  }
#pragma unroll
  for (int e = 0; e < E_NUM; e++) {
    double v = acc[e];
#pragma unroll
    for (int off = 32; off > 0; off >>= 1) v += __shfl_down(v, off, 64);
    acc[e] = v;
  }
  if (lane == 0) {
    int i0 = 0;
#pragma unroll
    for (int e = 1; e < E_NUM; e++) if (acc[e] > acc[i0]) i0 = e;
    int i1 = (i0 == 0) ? 1 : 0;
#pragma unroll
    for (int e = 0; e < E_NUM; e++) if (e != i0 && acc[e] > acc[i1]) i1 = e;
    double d = acc[i0] - acc[i1];          // >= 0
    double w0 = 1.0 / (1.0 + exp(-d));     // p0/(p0+p1)
    double w1 = 1.0 - w0;
    int p0 = atomicAdd(&cnt[i0], 1);
    list[i0 * N_TOK + p0] = n; wl[i0 * N_TOK + p0] = (float)w0;
    int p1 = atomicAdd(&cnt[i1], 1);
    list[i1 * N_TOK + p1] = n; wl[i1 * N_TOK + p1] = (float)w1;
  }
}

// ---------------- prefix sum + two block tables (SEG=128 and SEG=256) ----------------
__global__ void prefix_kernel(const int* __restrict__ cnt, int* __restrict__ rowbase,
                              int* __restrict__ btab128, int* __restrict__ btab256) {
  if (threadIdx.x == 0) {
    int s = 0, nb = 0, nb2 = 0;
    for (int e = 0; e < E_NUM; e++) {
      rowbase[e] = s;
      for (int m0 = 0; m0 < cnt[e]; m0 += 128) { btab128[2 * nb] = e; btab128[2 * nb + 1] = m0; nb++; }
      for (int m0 = 0; m0 < cnt[e]; m0 += 256) { btab256[2 * nb2] = e; btab256[2 * nb2 + 1] = m0; nb2++; }
      s += cnt[e];
    }
    for (; nb < MAXB; nb++) { btab128[2 * nb] = -1; btab128[2 * nb + 1] = 0; }
    for (; nb2 < MAXB2; nb2++) { btab256[2 * nb2] = -1; btab256[2 * nb2 + 1] = 0; }
  }
}

// ---------------- gather + convert: Xg[rb+p] = bf16(x[list[e][p]]) ----------------
__global__ void gather_x_kernel(const float* __restrict__ x, const int* __restrict__ cnt,
                                const int* __restrict__ rowbase, const int* __restrict__ list,
                                u16* __restrict__ Xg) {
  const int e = blockIdx.y;
  const int p = blockIdx.x * 4 + (threadIdx.x >> 6);
  if (p >= cnt[e]) return;
  const int lane = threadIdx.x & 63;
  const int tok = list[e * N_TOK + p];
  const float* src = x + (size_t)tok * C_DIM;
  u16* dst = Xg + (size_t)(rowbase[e] + p) * C_DIM;
#pragma unroll
  for (int i = 0; i < 4; i++) {
    float4 v = *(const float4*)(src + lane * 4 + i * 256);
    ushort4 o;
    o.x = f2bf(v.x); o.y = f2bf(v.y); o.z = f2bf(v.z); o.w = f2bf(v.w);
    *(ushort4*)(dst + lane * 4 + i * 256) = o;
  }
}

// ======== gemm1: 256x256 tile, 1024 threads (16 waves/CU), depth-3, linear ========
// h = gelu(Xg @ W1t^T + b1). 96 wave-load-instrs in flight per CU; AI=128 flop/B.
template<int NN0, int K>
__global__ __launch_bounds__(1024, 4) void gemm_wide_kernel(
    const u16* __restrict__ A, const u16* __restrict__ Wt, const float* __restrict__ bias_,
    const int* __restrict__ btab, const int* __restrict__ cnt, const int* __restrict__ rowbase,
    u16* __restrict__ hout) {
  constexpr int NTOT = NN0 * 256;
  constexpr int NT = K / 32;        // half-tile phases
  constexpr int TOT = MAXB2 * NN0;  // grid (TOT % 8 == 0)

  __shared__ __align__(16) u16 ldsA[4 * 256 * 32];  // 64 KB, 4 slots
  __shared__ __align__(16) u16 ldsB[4 * 256 * 32];  // 64 KB

  // bijective XCD chunking; n0-minor: co-resident blocks share A-panels
  const int L = (blockIdx.x & 7) * (TOT / 8) + (blockIdx.x >> 3);
  const int bx = L / NN0;
  const int n0 = (L % NN0) * 256;

  const int e = btab[bx * 2];
  if (e < 0) return;
  const int m0 = btab[bx * 2 + 1];
  const int count = cnt[e];
  const int rb = rowbase[e];

  const int tid = threadIdx.x;
  const int lane = tid & 63;
  const int wid = tid >> 6;          // 0..15
  const int wr = wid >> 2, wc = wid & 3;
  const int l15 = lane & 15, l4 = lane >> 4;

  // staging: thread t -> row t>>2 (0..255), 16B pos (t&3). LINEAR source (coalesced).
  const int srow = tid >> 2;
  const int spos = (tid & 3) * 8;
  const u16* aptr = A + (size_t)(rb + min(m0 + srow, count - 1)) * K + spos;
  const u16* bptr = Wt + ((size_t)e * NTOT + n0 + srow) * K + spos;

  const int paoff = (wr * 64 + l15) * 32 + l4 * 8;
  const int pboff = (wc * 64 + l15) * 32 + l4 * 8;

  f32x4 acc[4][4];
#pragma unroll
  for (int i = 0; i < 4; i++)
#pragma unroll
    for (int j = 0; j < 4; j++) acc[i][j] = {0.f, 0.f, 0.f, 0.f};

  auto STAGE = [&](int h) {    // half-tile h -> slot h&3; 2 loads/thread
    const int ko = h * 32;
    gl_lds16(aptr + ko, ldsA + (h & 3) * 8192 + tid * 8);
    gl_lds16(bptr + ko, ldsB + (h & 3) * 8192 + tid * 8);
  };

  auto PHASE = [&](int h) {
    const u16* pa = ldsA + (h & 3) * 8192 + paoff;
    const u16* pb = ldsB + (h & 3) * 8192 + pboff;
    bf16x8 av[4], bv[4];
#pragma unroll
    for (int i = 0; i < 4; i++) av[i] = *(const bf16x8*)(pa + i * 512);
#pragma unroll
    for (int j = 0; j < 4; j++) bv[j] = *(const bf16x8*)(pb + j * 512);
#pragma unroll
    for (int i = 0; i < 4; i++)
#pragma unroll
      for (int j = 0; j < 4; j++)
        acc[i][j] = __builtin_amdgcn_mfma_f32_16x16x32_bf16(av[i], bv[j], acc[i][j], 0, 0, 0);
  };

  // depth-3 prefetch: 3 half-tiles (6 loads/wave) in flight; vmcnt never 0 in loop
  STAGE(0); STAGE(1); STAGE(2);
  for (int h = 0; h < NT - 3; ++h) {
    STAGE(h + 3);           // slot (h+3)&3 == (h-1)&3, released by prev end-barrier
    wait_bar<6>();          // h's 2 loads landed; h+1..h+3 may fly
    PHASE(h);
    bar_only();             // release slot h
  }
  wait_bar<4>(); PHASE(NT - 3); bar_only();
  wait_bar<2>(); PHASE(NT - 2); bar_only();
  wait_bar<0>(); PHASE(NT - 1);

  // epilogue: bias + exact gelu -> bf16 h
#pragma unroll
  for (int i = 0; i < 4; i++) {
    const int rloc = wr * 64 + i * 16 + l4 * 4;
#pragma unroll
    for (int j = 0; j < 4; j++) {
      const int col = n0 + wc * 64 + j * 16 + l15;
      const float bias = bias_[e * NTOT + col];
#pragma unroll
      for (int rr = 0; rr < 4; rr++) {
        const int m = m0 + rloc + rr;
        if (m < count) {
          float v = acc[i][j][rr] + bias;
          float g = 0.5f * v * (1.0f + erff(v * 0.70710678118654752f));
          hout[(size_t)(rb + m) * D_DIM + col] = f2bf(g);
        }
      }
    }
  }
}

// ------- gemm2 (proven R7 config): 128x128, 256 threads, 4 blocks/CU, cohorts -------
// out += w*(h @ W2t^T + b2)
template<int NN0, int K>
__global__ __launch_bounds__(256, 4) void gemm_tlp_kernel(
    const u16* __restrict__ A, const u16* __restrict__ Wt, const float* __restrict__ bias_,
    const int* __restrict__ btab, const int* __restrict__ cnt, const int* __restrict__ rowbase,
    const int* __restrict__ list, const float* __restrict__ wl,
    float* __restrict__ out) {
  constexpr int NTOT = NN0 * 128;
  constexpr int NT = K / 32;
  constexpr int NG = NN0 / 4;
  constexpr int TOT = MAXB * NN0;

  __shared__ __align__(16) u16 ldsA[2 * 128 * 32];
  __shared__ __align__(16) u16 ldsB[2 * 128 * 32];

  const int L = (blockIdx.x & 7) * (TOT / 8) + (blockIdx.x >> 3);
  const int coh = L >> 4, r = L & 15;
  const int bxg = coh / NG;
  const int n0g = coh % NG;
  const int bx = bxg * 4 + (r & 3);
  const int n0 = (n0g * 4 + (r >> 2)) * 128;

  const int e = btab[bx * 2];
  if (e < 0) return;
  const int m0 = btab[bx * 2 + 1];
  const int count = cnt[e];
  const int rb = rowbase[e];

  const int tid = threadIdx.x;
  const int lane = tid & 63;
  const int wid = tid >> 6;
  const int wm = (wid >> 1) * 64;
  const int wn = (wid & 1) * 64;
  const int l15 = lane & 15, l4 = lane >> 4;

  const int arow0 = tid >> 2, pos = (tid & 3) * 8;
  const u16* aptr0 = A + (size_t)(rb + min(m0 + arow0, count - 1)) * K + pos;
  const u16* aptr1 = A + (size_t)(rb + min(m0 + arow0 + 64, count - 1)) * K + pos;
  const u16* bptr0 = Wt + ((size_t)e * NTOT + n0 + arow0) * K + pos;
  const u16* bptr1 = Wt + ((size_t)e * NTOT + n0 + arow0 + 64) * K + pos;

  const int paoff = (wm + l15) * 32 + l4 * 8;
  const int pboff = (wn + l15) * 32 + l4 * 8;

  f32x4 acc[4][4];
#pragma unroll
  for (int i = 0; i < 4; i++)
#pragma unroll
    for (int j = 0; j < 4; j++) acc[i][j] = {0.f, 0.f, 0.f, 0.f};

  auto STAGE = [&](int t, int b) {
    u16* da = ldsA + b * 4096 + tid * 8;
    u16* db = ldsB + b * 4096 + tid * 8;
    const int ko = t * 32;
    gl_lds16(aptr0 + ko, da);
    gl_lds16(aptr1 + ko, da + 2048);
    gl_lds16(bptr0 + ko, db);
    gl_lds16(bptr1 + ko, db + 2048);
  };

  auto PHASE = [&](int b) {
    const u16* pa = ldsA + b * 4096 + paoff;
    const u16* pb = ldsB + b * 4096 + pboff;
    bf16x8 av[4], bv[4];
#pragma unroll
    for (int i = 0; i < 4; i++) av[i] = *(const bf16x8*)(pa + i * 512);
#pragma unroll
    for (int j = 0; j < 4; j++) bv[j] = *(const bf16x8*)(pb + j * 512);
#pragma unroll
    for (int i = 0; i < 4; i++)
#pragma unroll
      for (int j = 0; j < 4; j++)
        acc[i][j] = __builtin_amdgcn_mfma_f32_16x16x32_bf16(av[i], bv[j], acc[i][j], 0, 0, 0);
  };

  STAGE(0, 0);
#pragma unroll 2
  for (int t = 0; t < NT - 1; ++t) {
    STAGE(t + 1, (t + 1) & 1);
    wait_bar<4>();
    PHASE(t & 1);
    bar_only();
  }
  wait_bar<0>();
  PHASE((NT - 1) & 1);

  const int* lst = list + e * N_TOK;
  const float* wlst = wl + e * N_TOK;
#pragma unroll
  for (int i = 0; i < 4; i++) {
    const int rloc = wm + i * 16 + l4 * 4;
#pragma unroll
    for (int j = 0; j < 4; j++) {
      const int col = n0 + wn + j * 16 + l15;
      const float bias = bias_[e * NTOT + col];
#pragma unroll
      for (int rr = 0; rr < 4; rr++) {
        const int m = m0 + rloc + rr;
        if (m < count) {
          const int tk = lst[m];
          atomicAdd(out + (size_t)tk * C_DIM + col, wlst[m] * (acc[i][j][rr] + bias));
        }
      }
    }
  }
}

extern "C" void kernel_launch(void* const* d_in, const int* in_sizes, int n_in,
                              void* d_out, int out_size, void* d_ws, size_t ws_size,
                              hipStream_t stream) {
  const float* x  = (const float*)d_in[0];
  const float* rw = (const float*)d_in[1];
  const float* W1 = (const float*)d_in[2];
  const float* b1 = (const float*)d_in[3];
  const float* W2 = (const float*)d_in[4];
  const float* b2 = (const float*)d_in[5];
  float* out = (float*)d_out;

  char* ws = (char*)d_ws;
  u16* W1t     = (u16*)(ws);                      // 50,331,648 B
  u16* Xg      = (u16*)(ws + 50331648);           // 33,554,432 B (overlaid by W2t after gemm1)
  u16* W2t     = (u16*)(ws + 50331648);           // 50,331,648 B (written AFTER gemm1)
  int* cnt     = (int*)(ws + 100663296);          // 256 B
  int* rowbase = (int*)(ws + 100663552);          // 256 B
  int* list    = (int*)(ws + 100663808);          // 262,144 B
  float* wl    = (float*)(ws + 100925952);        // 262,144 B
  int* btab128 = (int*)(ws + 101188096);          // 2,048 B
  int* btab256 = (int*)(ws + 101190144);          // 1,024 B
  u16* h       = (u16*)(ws + 101191168);          // 100,663,296 B -> end 201,854,464

  zero_init_kernel<<<(out_size + 255) / 256, 256, 0, stream>>>(out, out_size, cnt);
  router_kernel<<<N_TOK / 4, 256, 0, stream>>>(x, rw, cnt, list, wl);
  prefix_kernel<<<1, 64, 0, stream>>>(cnt, rowbase, btab128, btab256);
  gather_x_kernel<<<dim3(N_TOK / 4, E_NUM), 256, 0, stream>>>(x, cnt, rowbase, list, Xg);
  // W1 [E][C][D] f32 -> W1t [E][D][C] bf16
  transpose_conv_kernel<C_DIM, D_DIM><<<dim3(D_DIM / 64, C_DIM / 64, E_NUM), 256, 0, stream>>>(W1, W1t);
  gemm_wide_kernel<D_DIM / 256, C_DIM><<<MAXB2 * (D_DIM / 256), 1024, 0, stream>>>(
      Xg, W1t, b1, btab256, cnt, rowbase, h);
  // W2 [E][D][C] f32 -> W2t [E][C][D] bf16
  transpose_conv_kernel<D_DIM, C_DIM><<<dim3(C_DIM / 64, D_DIM / 64, E_NUM), 256, 0, stream>>>(W2, W2t);
  gemm_tlp_kernel<8, D_DIM><<<MAXB * 8, 256, 0, stream>>>(
      h, W2t, b2, btab128, cnt, rowbase, list, wl, out);
}

// Round 10
// 680.259 us; speedup vs baseline: 1.0376x; 1.0266x over previous
//
#include <hip/hip_runtime.h>
#include <math.h>

#define N_TOK 8192
#define C_DIM 1024
#define D_DIM 3072
#define E_NUM 8
#define SEG 128
#define MAXB 136   // sum ceil(cnt_e/128) <= 128 + 8; MAXB % 4 == 0

typedef unsigned short u16;
typedef unsigned int u32;
typedef __attribute__((ext_vector_type(8))) short bf16x8;
typedef __attribute__((ext_vector_type(4))) float f32x4;

__device__ __forceinline__ u16 f2bf(float f) {
  u32 u = __builtin_bit_cast(unsigned int, f);
  u = (u + 0x7FFFu + ((u >> 16) & 1u)) >> 16;
  return (u16)u;
}

__device__ __forceinline__ void gl_lds16(const void* g, void* l) {
  __builtin_amdgcn_global_load_lds(
      (const __attribute__((address_space(1))) unsigned int*)g,
      (__attribute__((address_space(3))) unsigned int*)l, 16, 0, 0);
}

// T4 idiom per m201 template: BARE counted vmcnt (no memory clobber -> no hidden
// vmcnt(0) drain at the asm boundary) + sched_barrier pin + builtin s_barrier.
template<int N> __device__ __forceinline__ void vm_wait() {
  if constexpr (N == 0) asm volatile("s_waitcnt vmcnt(0)");
  else if constexpr (N == 4) asm volatile("s_waitcnt vmcnt(4)");
  __builtin_amdgcn_sched_barrier(0);
}

// ---------------- init: zero output (incl aux loss) + counters ----------------
__global__ void zero_init_kernel(float* __restrict__ out, int n, int* __restrict__ cnt) {
  int i = blockIdx.x * 256 + threadIdx.x;
  if (i < n) out[i] = 0.0f;
  if (i < E_NUM) cnt[i] = 0;
}

// -------- transpose+convert: in [E][R][CC] f32 -> out [E][CC][R] bf16 --------
template<int R, int CC>
__global__ __launch_bounds__(256) void transpose_conv_kernel(
    const float* __restrict__ in, u16* __restrict__ outp) {
  __shared__ float t[64][65];
  const int e = blockIdx.z;
  const int r0 = blockIdx.y * 64;
  const int c0 = blockIdx.x * 64;
  const int tid = threadIdx.x;
  const int lr = tid >> 4;
  const int lc = (tid & 15) * 4;
#pragma unroll
  for (int i = 0; i < 4; i++) {
    float4 v = *(const float4*)(in + ((size_t)e * R + r0 + lr + i * 16) * CC + c0 + lc);
    t[lr + i * 16][lc] = v.x; t[lr + i * 16][lc + 1] = v.y;
    t[lr + i * 16][lc + 2] = v.z; t[lr + i * 16][lc + 3] = v.w;
  }
  __syncthreads();
  const int orow = tid >> 3;
  const int oc = (tid & 7) * 8;
#pragma unroll
  for (int i = 0; i < 2; i++) {
    const int d = orow + i * 32;
    union { u16 s[8]; uint4 v; } o;
#pragma unroll
    for (int j = 0; j < 8; j++) o.s[j] = f2bf(t[oc + j][d]);
    *(uint4*)(outp + ((size_t)e * CC + c0 + d) * R + r0 + oc) = o.v;
  }
}

// ---------------- router: logits (fp64), top-2, scatter ----------------
__global__ void router_kernel(const float* __restrict__ x, const float* __restrict__ rw,
                              int* __restrict__ cnt, int* __restrict__ list,
                              float* __restrict__ wl) {
  const int lane = threadIdx.x & 63;
  const int n = blockIdx.x * 4 + (threadIdx.x >> 6);
  const float* xr = x + (size_t)n * C_DIM;
  double acc[E_NUM];
#pragma unroll
  for (int e = 0; e < E_NUM; e++) acc[e] = 0.0;
  for (int c = lane; c < C_DIM; c += 64) {
    float xv = xr[c];
#pragma unroll
    for (int e = 0; e < E_NUM; e++) acc[e] += (double)xv * (double)rw[e * C_DIM + c];
  }
#pragma unroll
  for (int e = 0; e < E_NUM; e++) {
    double v = acc[e];
#pragma unroll
    for (int off = 32; off > 0; off >>= 1) v += __shfl_down(v, off, 64);
    acc[e] = v;
  }
  if (lane == 0) {
    int i0 = 0;
#pragma unroll
    for (int e = 1; e < E_NUM; e++) if (acc[e] > acc[i0]) i0 = e;
    int i1 = (i0 == 0) ? 1 : 0;
#pragma unroll
    for (int e = 0; e < E_NUM; e++) if (e != i0 && acc[e] > acc[i1]) i1 = e;
    double d = acc[i0] - acc[i1];          // >= 0
    double w0 = 1.0 / (1.0 + exp(-d));     // p0/(p0+p1)
    double w1 = 1.0 - w0;
    int p0 = atomicAdd(&cnt[i0], 1);
    list[i0 * N_TOK + p0] = n; wl[i0 * N_TOK + p0] = (float)w0;
    int p1 = atomicAdd(&cnt[i1], 1);
    list[i1 * N_TOK + p1] = n; wl[i1 * N_TOK + p1] = (float)w1;
  }
}

// ---------------- prefix sum + block table (SEG-row segments) ----------------
__global__ void prefix_kernel(const int* __restrict__ cnt, int* __restrict__ rowbase,
                              int* __restrict__ btab) {
  if (threadIdx.x == 0) {
    int s = 0, nb = 0;
    for (int e = 0; e < E_NUM; e++) {
      rowbase[e] = s;
      for (int m0 = 0; m0 < cnt[e]; m0 += SEG) { btab[2 * nb] = e; btab[2 * nb + 1] = m0; nb++; }
      s += cnt[e];
    }
    for (; nb < MAXB; nb++) { btab[2 * nb] = -1; btab[2 * nb + 1] = 0; }
  }
}

// ---------------- gather + convert: Xg[rb+p] = bf16(x[list[e][p]]) ----------------
__global__ void gather_x_kernel(const float* __restrict__ x, const int* __restrict__ cnt,
                                const int* __restrict__ rowbase, const int* __restrict__ list,
                                u16* __restrict__ Xg) {
  const int e = blockIdx.y;
  const int p = blockIdx.x * 4 + (threadIdx.x >> 6);
  if (p >= cnt[e]) return;
  const int lane = threadIdx.x & 63;
  const int tok = list[e * N_TOK + p];
  const float* src = x + (size_t)tok * C_DIM;
  u16* dst = Xg + (size_t)(rowbase[e] + p) * C_DIM;
#pragma unroll
  for (int i = 0; i < 4; i++) {
    float4 v = *(const float4*)(src + lane * 4 + i * 256);
    ushort4 o;
    o.x = f2bf(v.x); o.y = f2bf(v.y); o.z = f2bf(v.z); o.w = f2bf(v.w);
    *(ushort4*)(dst + lane * 4 + i * 256) = o;
  }
}

// ------- 128x128 tile, 256 threads, 32KB LDS dbuf, 4 blocks/CU (TLP + true T4) -------
// EPI=1: h = gelu(Xg @ W1t^T + b1)     A=Xg dense rows, Wt=[E][D][C]
// EPI=2: out += w*(h @ W2t^T + b2)     A=h dense rows,  Wt=[E][C][D]
template<int NN0, int K, int EPI>
__global__ __launch_bounds__(256, 4) void gemm_tlp_kernel(
    const u16* __restrict__ A, const u16* __restrict__ Wt, const float* __restrict__ bias_,
    const int* __restrict__ btab, const int* __restrict__ cnt, const int* __restrict__ rowbase,
    const int* __restrict__ list, const float* __restrict__ wl,
    u16* __restrict__ hout, float* __restrict__ out) {
  constexpr int NTOT = NN0 * 128;
  constexpr int NT = K / 32;       // K-steps
  constexpr int NG = NN0 / 4;      // n0 cohort groups
  constexpr int TOT = MAXB * NN0;  // grid size (TOT % 8 == 0)

  __shared__ __align__(16) u16 ldsA[2 * 128 * 32];  // 16 KB
  __shared__ __align__(16) u16 ldsB[2 * 128 * 32];  // 16 KB

  // bijective XCD chunking, then 4x4 cohort decode
  const int L = (blockIdx.x & 7) * (TOT / 8) + (blockIdx.x >> 3);
  const int coh = L >> 4, r = L & 15;
  const int bxg = coh / NG;
  const int n0g = coh % NG;
  const int bx = bxg * 4 + (r & 3);
  const int n0 = (n0g * 4 + (r >> 2)) * 128;

  const int e = btab[bx * 2];
  if (e < 0) return;
  const int m0 = btab[bx * 2 + 1];
  const int count = cnt[e];
  const int rb = rowbase[e];

  const int tid = threadIdx.x;
  const int lane = tid & 63;
  const int wid = tid >> 6;
  const int wm = (wid >> 1) * 64;
  const int wn = (wid & 1) * 64;
  const int l15 = lane & 15, l4 = lane >> 4;

  // staging: chunk c = tid + r*256; row = c>>2; 16B pos = (c&3)*8 u16. LINEAR (coalesced).
  const int arow0 = tid >> 2, pos = (tid & 3) * 8;
  const u16* aptr0 = A + (size_t)(rb + min(m0 + arow0, count - 1)) * K + pos;
  const u16* aptr1 = A + (size_t)(rb + min(m0 + arow0 + 64, count - 1)) * K + pos;
  const u16* bptr0 = Wt + ((size_t)e * NTOT + n0 + arow0) * K + pos;
  const u16* bptr1 = Wt + ((size_t)e * NTOT + n0 + arow0 + 64) * K + pos;

  const int paoff = (wm + l15) * 32 + l4 * 8;
  const int pboff = (wn + l15) * 32 + l4 * 8;

  f32x4 acc[4][4];
#pragma unroll
  for (int i = 0; i < 4; i++)
#pragma unroll
    for (int j = 0; j < 4; j++) acc[i][j] = {0.f, 0.f, 0.f, 0.f};

  auto STAGE = [&](int t, int b) {
    u16* da = ldsA + b * 4096 + tid * 8;
    u16* db = ldsB + b * 4096 + tid * 8;
    const int ko = t * 32;
    gl_lds16(aptr0 + ko, da);
    gl_lds16(aptr1 + ko, da + 2048);
    gl_lds16(bptr0 + ko, db);
    gl_lds16(bptr1 + ko, db + 2048);
  };

  auto PHASE = [&](int b) {
    const u16* pa = ldsA + b * 4096 + paoff;
    const u16* pb = ldsB + b * 4096 + pboff;
    bf16x8 av[4], bv[4];
#pragma unroll
    for (int i = 0; i < 4; i++) av[i] = *(const bf16x8*)(pa + i * 512);
#pragma unroll
    for (int j = 0; j < 4; j++) bv[j] = *(const bf16x8*)(pb + j * 512);
#pragma unroll
    for (int i = 0; i < 4; i++)
#pragma unroll
      for (int j = 0; j < 4; j++)
        acc[i][j] = __builtin_amdgcn_mfma_f32_16x16x32_bf16(av[i], bv[j], acc[i][j], 0, 0, 0);
  };

  // double-buffer; counted vmcnt with NO hidden drain: t+1's 4 loads stay in
  // flight across the barrier (T4). Never vmcnt(0) inside the loop.
  STAGE(0, 0);
  for (int t = 0; t < NT - 1; ++t) {
    STAGE(t + 1, (t + 1) & 1);
    vm_wait<4>();                        // t's 4 loads landed; t+1's may fly
    __builtin_amdgcn_s_barrier();        // all waves: buf t&1 fully staged
    __builtin_amdgcn_sched_barrier(0);   // pin: no ds_read hoists above
    PHASE(t & 1);
    __builtin_amdgcn_s_barrier();        // all waves done reading buf t&1
  }
  vm_wait<0>();
  __builtin_amdgcn_s_barrier();
  __builtin_amdgcn_sched_barrier(0);
  PHASE((NT - 1) & 1);

  // ---------------- epilogue ----------------
  if constexpr (EPI == 1) {
#pragma unroll
    for (int i = 0; i < 4; i++) {
      const int rloc = wm + i * 16 + l4 * 4;
#pragma unroll
      for (int j = 0; j < 4; j++) {
        const int col = n0 + wn + j * 16 + l15;
        const float bias = bias_[e * NTOT + col];
#pragma unroll
        for (int rr = 0; rr < 4; rr++) {
          const int m = m0 + rloc + rr;
          if (m < count) {
            float v = acc[i][j][rr] + bias;
            float g = 0.5f * v * (1.0f + erff(v * 0.70710678118654752f));
            hout[(size_t)(rb + m) * D_DIM + col] = f2bf(g);
          }
        }
      }
    }
  } else {
    const int* lst = list + e * N_TOK;
    const float* wlst = wl + e * N_TOK;
#pragma unroll
    for (int i = 0; i < 4; i++) {
      const int rloc = wm + i * 16 + l4 * 4;
#pragma unroll
      for (int j = 0; j < 4; j++) {
        const int col = n0 + wn + j * 16 + l15;
        const float bias = bias_[e * NTOT + col];
#pragma unroll
        for (int rr = 0; rr < 4; rr++) {
          const int m = m0 + rloc + rr;
          if (m < count) {
            const int tk = lst[m];
            atomicAdd(out + (size_t)tk * C_DIM + col, wlst[m] * (acc[i][j][rr] + bias));
          }
        }
      }
    }
  }
}

extern "C" void kernel_launch(void* const* d_in, const int* in_sizes, int n_in,
                              void* d_out, int out_size, void* d_ws, size_t ws_size,
                              hipStream_t stream) {
  const float* x  = (const float*)d_in[0];
  const float* rw = (const float*)d_in[1];
  const float* W1 = (const float*)d_in[2];
  const float* b1 = (const float*)d_in[3];
  const float* W2 = (const float*)d_in[4];
  const float* b2 = (const float*)d_in[5];
  float* out = (float*)d_out;

  char* ws = (char*)d_ws;
  u16* W1t    = (u16*)(ws);                      // 50,331,648 B
  u16* Xg     = (u16*)(ws + 50331648);           // 33,554,432 B (overlaid by W2t after gemm1)
  u16* W2t    = (u16*)(ws + 50331648);           // 50,331,648 B (written AFTER gemm1)
  int* cnt    = (int*)(ws + 100663296);          // 256 B
  int* rowbase= (int*)(ws + 100663552);          // 256 B
  int* list   = (int*)(ws + 100663808);          // 262,144 B
  float* wl   = (float*)(ws + 100925952);        // 262,144 B
  int* btab   = (int*)(ws + 101188096);          // 2,048 B
  u16* h      = (u16*)(ws + 101190656);          // 100,663,296 B -> end 201,853,952

  zero_init_kernel<<<(out_size + 255) / 256, 256, 0, stream>>>(out, out_size, cnt);
  router_kernel<<<N_TOK / 4, 256, 0, stream>>>(x, rw, cnt, list, wl);
  prefix_kernel<<<1, 64, 0, stream>>>(cnt, rowbase, btab);
  gather_x_kernel<<<dim3(N_TOK / 4, E_NUM), 256, 0, stream>>>(x, cnt, rowbase, list, Xg);
  // W1 [E][C][D] f32 -> W1t [E][D][C] bf16
  transpose_conv_kernel<C_DIM, D_DIM><<<dim3(D_DIM / 64, C_DIM / 64, E_NUM), 256, 0, stream>>>(W1, W1t);
  gemm_tlp_kernel<24, C_DIM, 1><<<MAXB * 24, 256, 0, stream>>>(
      Xg, W1t, b1, btab, cnt, rowbase, list, wl, h, out);
  // W2 [E][D][C] f32 -> W2t [E][C][D] bf16
  transpose_conv_kernel<D_DIM, C_DIM><<<dim3(C_DIM / 64, D_DIM / 64, E_NUM), 256, 0, stream>>>(W2, W2t);
  gemm_tlp_kernel<8, D_DIM, 2><<<MAXB * 8, 256, 0, stream>>>(
      h, W2t, b2, btab, cnt, rowbase, list, wl, h, out);
}

// Round 11
// 661.816 us; speedup vs baseline: 1.0665x; 1.0279x over previous
//
#include <hip/hip_runtime.h>
#include <math.h>

#define N_TOK 8192
#define C_DIM 1024
#define D_DIM 3072
#define E_NUM 8
#define SEG 128
#define MAXB 136   // sum ceil(cnt_e/128) <= 128 + 8; MAXB % 4 == 0

typedef unsigned short u16;
typedef unsigned int u32;
typedef __attribute__((ext_vector_type(8))) short bf16x8;
typedef __attribute__((ext_vector_type(4))) float f32x4;

__device__ __forceinline__ u16 f2bf(float f) {
  u32 u = __builtin_bit_cast(unsigned int, f);
  u = (u + 0x7FFFu + ((u >> 16) & 1u)) >> 16;
  return (u16)u;
}

// ---------------- init: zero output (incl aux loss) + counters ----------------
__global__ void zero_init_kernel(float* __restrict__ out, int n, int* __restrict__ cnt) {
  int i = blockIdx.x * 256 + threadIdx.x;
  if (i < n) out[i] = 0.0f;
  if (i < E_NUM) cnt[i] = 0;
}

// -------- transpose+convert: in [E][R][CC] f32 -> out [E][CC][R] bf16 --------
template<int R, int CC>
__global__ __launch_bounds__(256) void transpose_conv_kernel(
    const float* __restrict__ in, u16* __restrict__ outp) {
  __shared__ float t[64][65];
  const int e = blockIdx.z;
  const int r0 = blockIdx.y * 64;
  const int c0 = blockIdx.x * 64;
  const int tid = threadIdx.x;
  const int lr = tid >> 4;
  const int lc = (tid & 15) * 4;
#pragma unroll
  for (int i = 0; i < 4; i++) {
    float4 v = *(const float4*)(in + ((size_t)e * R + r0 + lr + i * 16) * CC + c0 + lc);
    t[lr + i * 16][lc] = v.x; t[lr + i * 16][lc + 1] = v.y;
    t[lr + i * 16][lc + 2] = v.z; t[lr + i * 16][lc + 3] = v.w;
  }
  __syncthreads();
  const int orow = tid >> 3;
  const int oc = (tid & 7) * 8;
#pragma unroll
  for (int i = 0; i < 2; i++) {
    const int d = orow + i * 32;
    union { u16 s[8]; uint4 v; } o;
#pragma unroll
    for (int j = 0; j < 8; j++) o.s[j] = f2bf(t[oc + j][d]);
    *(uint4*)(outp + ((size_t)e * CC + c0 + d) * R + r0 + oc) = o.v;
  }
}

// ---------------- router: logits (fp64), top-2, scatter ----------------
__global__ void router_kernel(const float* __restrict__ x, const float* __restrict__ rw,
                              int* __restrict__ cnt, int* __restrict__ list,
                              float* __restrict__ wl) {
  const int lane = threadIdx.x & 63;
  const int n = blockIdx.x * 4 + (threadIdx.x >> 6);
  const float* xr = x + (size_t)n * C_DIM;
  double acc[E_NUM];
#pragma unroll
  for (int e = 0; e < E_NUM; e++) acc[e] = 0.0;
  for (int c = lane; c < C_DIM; c += 64) {
    float xv = xr[c];
#pragma unroll
    for (int e = 0; e < E_NUM; e++) acc[e] += (double)xv * (double)rw[e * C_DIM + c];
  }
#pragma unroll
  for (int e = 0; e < E_NUM; e++) {
    double v = acc[e];
#pragma unroll
    for (int off = 32; off > 0; off >>= 1) v += __shfl_down(v, off, 64);
    acc[e] = v;
  }
  if (lane == 0) {
    int i0 = 0;
#pragma unroll
    for (int e = 1; e < E_NUM; e++) if (acc[e] > acc[i0]) i0 = e;
    int i1 = (i0 == 0) ? 1 : 0;
#pragma unroll
    for (int e = 0; e < E_NUM; e++) if (e != i0 && acc[e] > acc[i1]) i1 = e;
    double d = acc[i0] - acc[i1];          // >= 0
    double w0 = 1.0 / (1.0 + exp(-d));     // p0/(p0+p1)
    double w1 = 1.0 - w0;
    int p0 = atomicAdd(&cnt[i0], 1);
    list[i0 * N_TOK + p0] = n; wl[i0 * N_TOK + p0] = (float)w0;
    int p1 = atomicAdd(&cnt[i1], 1);
    list[i1 * N_TOK + p1] = n; wl[i1 * N_TOK + p1] = (float)w1;
  }
}

// ---------------- prefix sum + block table (SEG-row segments) ----------------
__global__ void prefix_kernel(const int* __restrict__ cnt, int* __restrict__ rowbase,
                              int* __restrict__ btab) {
  if (threadIdx.x == 0) {
    int s = 0, nb = 0;
    for (int e = 0; e < E_NUM; e++) {
      rowbase[e] = s;
      for (int m0 = 0; m0 < cnt[e]; m0 += SEG) { btab[2 * nb] = e; btab[2 * nb + 1] = m0; nb++; }
      s += cnt[e];
    }
    for (; nb < MAXB; nb++) { btab[2 * nb] = -1; btab[2 * nb + 1] = 0; }
  }
}

// ---------------- gather + convert: Xg[rb+p] = bf16(x[list[e][p]]) ----------------
__global__ void gather_x_kernel(const float* __restrict__ x, const int* __restrict__ cnt,
                                const int* __restrict__ rowbase, const int* __restrict__ list,
                                u16* __restrict__ Xg) {
  const int e = blockIdx.y;
  const int p = blockIdx.x * 4 + (threadIdx.x >> 6);
  if (p >= cnt[e]) return;
  const int lane = threadIdx.x & 63;
  const int tok = list[e * N_TOK + p];
  const float* src = x + (size_t)tok * C_DIM;
  u16* dst = Xg + (size_t)(rowbase[e] + p) * C_DIM;
#pragma unroll
  for (int i = 0; i < 4; i++) {
    float4 v = *(const float4*)(src + lane * 4 + i * 256);
    ushort4 o;
    o.x = f2bf(v.x); o.y = f2bf(v.y); o.z = f2bf(v.z); o.w = f2bf(v.w);
    *(ushort4*)(dst + lane * 4 + i * 256) = o;
  }
}

// ---- 128x128 tile, 256 threads, 4 blocks/CU, REG-STAGED (T14) + cohorts ----
// Staging via global_load_dwordx4 -> VGPR -> ds_write: goes through TCP/L1->L2
// allocate path (unlike global_load_lds), so cohort panel-sharing can hit cache.
// Loads for t+1 issued BEFORE phase t; no vmcnt drain at barriers (raw s_barrier).
// EPI=1: h = gelu(Xg @ W1t^T + b1)     A=Xg dense rows, Wt=[E][D][C]
// EPI=2: out += w*(h @ W2t^T + b2)     A=h dense rows,  Wt=[E][C][D]
template<int NN0, int K, int EPI>
__global__ __launch_bounds__(256, 4) void gemm_rs_kernel(
    const u16* __restrict__ A, const u16* __restrict__ Wt, const float* __restrict__ bias_,
    const int* __restrict__ btab, const int* __restrict__ cnt, const int* __restrict__ rowbase,
    const int* __restrict__ list, const float* __restrict__ wl,
    u16* __restrict__ hout, float* __restrict__ out) {
  constexpr int NTOT = NN0 * 128;
  constexpr int NT = K / 32;       // K-steps
  constexpr int NG = NN0 / 4;      // n0 cohort groups
  constexpr int TOT = MAXB * NN0;  // grid size (TOT % 8 == 0)

  __shared__ __align__(16) u16 ldsA[2 * 128 * 32];  // 16 KB
  __shared__ __align__(16) u16 ldsB[2 * 128 * 32];  // 16 KB

  // bijective XCD chunking, then 4x4 cohort decode:
  // 4 consecutive blocks (same CU) share the B-panel (L1/L2);
  // the 4-CU cohort shares A-panels (L2).
  const int L = (blockIdx.x & 7) * (TOT / 8) + (blockIdx.x >> 3);
  const int coh = L >> 4, r = L & 15;
  const int bxg = coh / NG;
  const int n0g = coh % NG;
  const int bx = bxg * 4 + (r & 3);
  const int n0 = (n0g * 4 + (r >> 2)) * 128;

  const int e = btab[bx * 2];
  if (e < 0) return;
  const int m0 = btab[bx * 2 + 1];
  const int count = cnt[e];
  const int rb = rowbase[e];

  const int tid = threadIdx.x;
  const int lane = tid & 63;
  const int wid = tid >> 6;
  const int wm = (wid >> 1) * 64;
  const int wn = (wid & 1) * 64;
  const int l15 = lane & 15, l4 = lane >> 4;

  // staging addresses: row = tid>>2 (+64), 16B pos = (tid&3)*8 u16. LINEAR.
  const int arow0 = tid >> 2, pos = (tid & 3) * 8;
  const u16* aptr0 = A + (size_t)(rb + min(m0 + arow0, count - 1)) * K + pos;
  const u16* aptr1 = A + (size_t)(rb + min(m0 + arow0 + 64, count - 1)) * K + pos;
  const u16* bptr0 = Wt + ((size_t)e * NTOT + n0 + arow0) * K + pos;
  const u16* bptr1 = Wt + ((size_t)e * NTOT + n0 + arow0 + 64) * K + pos;

  const int paoff = (wm + l15) * 32 + l4 * 8;
  const int pboff = (wn + l15) * 32 + l4 * 8;

  f32x4 acc[4][4];
#pragma unroll
  for (int i = 0; i < 4; i++)
#pragma unroll
    for (int j = 0; j < 4; j++) acc[i][j] = {0.f, 0.f, 0.f, 0.f};

  uint4 ra0, ra1, rb0, rb1;                 // in-flight staging registers
  auto LOAD = [&](int t) {
    const int ko = t * 32;
    ra0 = *(const uint4*)(aptr0 + ko);
    ra1 = *(const uint4*)(aptr1 + ko);
    rb0 = *(const uint4*)(bptr0 + ko);
    rb1 = *(const uint4*)(bptr1 + ko);
  };
  auto WRITE = [&](int b) {                  // compiler inserts vmcnt waits
    *(uint4*)(ldsA + b * 4096 + tid * 8) = ra0;
    *(uint4*)(ldsA + b * 4096 + 2048 + tid * 8) = ra1;
    *(uint4*)(ldsB + b * 4096 + tid * 8) = rb0;
    *(uint4*)(ldsB + b * 4096 + 2048 + tid * 8) = rb1;
  };

  auto PHASE = [&](int b) {
    const u16* pa = ldsA + b * 4096 + paoff;
    const u16* pb = ldsB + b * 4096 + pboff;
    bf16x8 av[4], bv[4];
#pragma unroll
    for (int i = 0; i < 4; i++) av[i] = *(const bf16x8*)(pa + i * 512);
#pragma unroll
    for (int j = 0; j < 4; j++) bv[j] = *(const bf16x8*)(pb + j * 512);
#pragma unroll
    for (int i = 0; i < 4; i++)
#pragma unroll
      for (int j = 0; j < 4; j++)
        acc[i][j] = __builtin_amdgcn_mfma_f32_16x16x32_bf16(av[i], bv[j], acc[i][j], 0, 0, 0);
  };

  // prologue: tile 0 staged and published
  LOAD(0);
  WRITE(0);
  asm volatile("s_waitcnt lgkmcnt(0)");
  __builtin_amdgcn_sched_barrier(0);

  for (int t = 0; t < NT - 1; ++t) {
    LOAD(t + 1);                         // VMEM in flight; hidden under phase t
    __builtin_amdgcn_s_barrier();        // publish WRITE(t&1) to all waves
    __builtin_amdgcn_sched_barrier(0);
    PHASE(t & 1);
    __builtin_amdgcn_s_barrier();        // all waves done reading buf (t+1)&1 [phase t-1]
    WRITE((t + 1) & 1);                  // vmcnt waits auto-inserted here
    asm volatile("s_waitcnt lgkmcnt(0)");
    __builtin_amdgcn_sched_barrier(0);
  }
  __builtin_amdgcn_s_barrier();
  __builtin_amdgcn_sched_barrier(0);
  PHASE((NT - 1) & 1);

  // ---------------- epilogue ----------------
  if constexpr (EPI == 1) {
#pragma unroll
    for (int i = 0; i < 4; i++) {
      const int rloc = wm + i * 16 + l4 * 4;
#pragma unroll
      for (int j = 0; j < 4; j++) {
        const int col = n0 + wn + j * 16 + l15;
        const float bias = bias_[e * NTOT + col];
#pragma unroll
        for (int rr = 0; rr < 4; rr++) {
          const int m = m0 + rloc + rr;
          if (m < count) {
            float v = acc[i][j][rr] + bias;
            float g = 0.5f * v * (1.0f + erff(v * 0.70710678118654752f));
            hout[(size_t)(rb + m) * D_DIM + col] = f2bf(g);
          }
        }
      }
    }
  } else {
    const int* lst = list + e * N_TOK;
    const float* wlst = wl + e * N_TOK;
#pragma unroll
    for (int i = 0; i < 4; i++) {
      const int rloc = wm + i * 16 + l4 * 4;
#pragma unroll
      for (int j = 0; j < 4; j++) {
        const int col = n0 + wn + j * 16 + l15;
        const float bias = bias_[e * NTOT + col];
#pragma unroll
        for (int rr = 0; rr < 4; rr++) {
          const int m = m0 + rloc + rr;
          if (m < count) {
            const int tk = lst[m];
            atomicAdd(out + (size_t)tk * C_DIM + col, wlst[m] * (acc[i][j][rr] + bias));
          }
        }
      }
    }
  }
}

extern "C" void kernel_launch(void* const* d_in, const int* in_sizes, int n_in,
                              void* d_out, int out_size, void* d_ws, size_t ws_size,
                              hipStream_t stream) {
  const float* x  = (const float*)d_in[0];
  const float* rw = (const float*)d_in[1];
  const float* W1 = (const float*)d_in[2];
  const float* b1 = (const float*)d_in[3];
  const float* W2 = (const float*)d_in[4];
  const float* b2 = (const float*)d_in[5];
  float* out = (float*)d_out;

  char* ws = (char*)d_ws;
  u16* W1t    = (u16*)(ws);                      // 50,331,648 B
  u16* Xg     = (u16*)(ws + 50331648);           // 33,554,432 B (overlaid by W2t after gemm1)
  u16* W2t    = (u16*)(ws + 50331648);           // 50,331,648 B (written AFTER gemm1)
  int* cnt    = (int*)(ws + 100663296);          // 256 B
  int* rowbase= (int*)(ws + 100663552);          // 256 B
  int* list   = (int*)(ws + 100663808);          // 262,144 B
  float* wl   = (float*)(ws + 100925952);        // 262,144 B
  int* btab   = (int*)(ws + 101188096);          // 2,048 B
  u16* h      = (u16*)(ws + 101190656);          // 100,663,296 B -> end 201,853,952

  zero_init_kernel<<<(out_size + 255) / 256, 256, 0, stream>>>(out, out_size, cnt);
  router_kernel<<<N_TOK / 4, 256, 0, stream>>>(x, rw, cnt, list, wl);
  prefix_kernel<<<1, 64, 0, stream>>>(cnt, rowbase, btab);
  gather_x_kernel<<<dim3(N_TOK / 4, E_NUM), 256, 0, stream>>>(x, cnt, rowbase, list, Xg);
  // W1 [E][C][D] f32 -> W1t [E][D][C] bf16
  transpose_conv_kernel<C_DIM, D_DIM><<<dim3(D_DIM / 64, C_DIM / 64, E_NUM), 256, 0, stream>>>(W1, W1t);
  gemm_rs_kernel<24, C_DIM, 1><<<MAXB * 24, 256, 0, stream>>>(
      Xg, W1t, b1, btab, cnt, rowbase, list, wl, h, out);
  // W2 [E][D][C] f32 -> W2t [E][C][D] bf16
  transpose_conv_kernel<D_DIM, C_DIM><<<dim3(C_DIM / 64, D_DIM / 64, E_NUM), 256, 0, stream>>>(W2, W2t);
  gemm_rs_kernel<8, D_DIM, 2><<<MAXB * 8, 256, 0, stream>>>(
      h, W2t, b2, btab, cnt, rowbase, list, wl, h, out);
}